// Round 5
// baseline (619.023 us; speedup 1.0000x reference)
//
#include <hip/hip_runtime.h>
#include <hip/hip_cooperative_groups.h>
#include <math.h>

namespace cg = cooperative_groups;

constexpr int NROW = 8192;
constexpr int FD   = 256;
constexpr int NZ   = 32;
constexpr int NB   = 512;

// ws layout (bytes), total 9437184 (same footprint that passed R2-R4):
//   0       scal[16]
//   1024    fpart[512]
//   3072    fpart1[512]
//   8192    f0[8192]
//   40960   f0sq[8192]
//   73728   nrm0[8192]
//   106496  nrm1[8192]
//   139264  u[8192]
//   172032  c0[256]
//   176128  part[512][256]  (Sf colsum partials; reused: cA[0..128) wA[128..256) vA[256..384))
//   700416  G0[256][256]
//   1048576 emb[8192][256]  (Gp[32][256][256] aliases it before apply)

struct P {
  const float* X; const float* linear; const float* dirv; const float* feat;
  float* out;
  float* scal; float* fpart; float* fpart1; float* f0; float* f0sq;
  float* nrm0; float* nrm1; float* u; float* c0; float* part; float* G0; float* emb;
};

__device__ __forceinline__ float f_of(float nj, float A, float B, float AB) {
  float inner = AB * nj;
  return A - (inner <= 0.f ? inner : 0.f) * B;
}
__device__ __forceinline__ float wred(float s) {
  #pragma unroll
  for (int off = 32; off; off >>= 1) s += __shfl_xor(s, off);
  return s;
}
__device__ __forceinline__ float dot4(float4 a, float4 b) {
  return a.x*b.x + a.y*b.y + a.z*b.z + a.w*b.w;
}

// P0: row norms of X + block partial sums
__device__ void P0(const P& p, int bid, float* sh) {
  int tid = threadIdx.x, wave = tid >> 6, lane = tid & 63;
  #pragma unroll
  for (int jj = 0; jj < 4; ++jj) {
    int row = bid*16 + wave*4 + jj;
    float4 v = *(const float4*)&p.X[(size_t)row*FD + lane*4];
    float t = wred(dot4(v, v));
    if (lane == 0) { p.nrm0[row] = t; sh[wave*4 + jj] = t; }
  }
  __syncthreads();
  if (tid == 0) { float s = 0; for (int j = 0; j < 16; ++j) s += sh[j]; p.fpart[bid] = s; }
}

// P1: block 0 only — a,b dots + F2 reduce + depth-0 scalars
__device__ void P1(const P& p, int bid, float* sh) {
  if (bid) return;
  int tid = threadIdx.x;
  if (tid < 64) {
    for (int i = 0; i < 2; ++i) {
      float pa = 0, pb = 0;
      for (int k = tid; k < FD; k += 64) {
        float l = p.linear[i*FD + k];
        pa += p.feat[i*FD + k]*l; pb += p.dirv[i*FD + k]*l;
      }
      pa = wred(pa); pb = wred(pb);
      if (tid == 0) { sh[480 + i] = pa; sh[482 + i] = pb; }
    }
  }
  float s = p.fpart[tid] + p.fpart[tid + 256];
  sh[tid] = s;
  __syncthreads();
  for (int off = 128; off; off >>= 1) {
    if (tid < off) sh[tid] += sh[tid + off];
    __syncthreads();
  }
  if (tid == 0) {
    float F2 = sh[0];
    float a = sh[480], b = sh[482];
    float sb = (b > 0.f) ? 1.f : ((b < 0.f) ? -1.f : 0.f);
    float B = sb / sqrtf(F2);
    p.scal[0] = a; p.scal[1] = sh[481]; p.scal[2] = b; p.scal[3] = sh[483];
    p.scal[4] = a; p.scal[5] = B; p.scal[6] = a * B;
  }
}

// Pf: f0/f0sq arrays + colsum partials of r0 = f0*X
__device__ void Pf(const P& p, int bid, float* sh) {
  int tid = threadIdx.x, r0 = bid*16;
  if (tid < 16) {
    float f = f_of(p.nrm0[r0 + tid], p.scal[4], p.scal[5], p.scal[6]);
    p.f0[r0 + tid] = f; p.f0sq[r0 + tid] = f*f; sh[tid] = f;
  }
  __syncthreads();
  float s = 0;
  #pragma unroll
  for (int j = 0; j < 16; ++j) s += sh[j] * p.X[(size_t)(r0 + j)*FD + tid];
  p.part[(size_t)bid*FD + tid] = s;
}

// P2: gram partials Gp[z] = sum_k f0sq[k] X[k][ca]^T X[k][cb]; no LDS, 4x4 acc
__device__ void P2(const P& p, int bid, float*) {
  const int z = bid >> 4, ti = bid & 3, tj = (bid >> 2) & 3;
  const int tid = threadIdx.x, tx = tid & 15, ty = tid >> 4;
  const size_t m0 = (size_t)z * 256;
  const float* Xk = p.X + m0*FD;
  const int ca = ti*64 + ty*4, cb = tj*64 + tx*4;
  float acc[4][4] = {};
  for (int mc = 0; mc < 256; mc += 4) {
    float4 f2 = *(const float4*)&p.f0sq[m0 + mc];
    float fq[4] = {f2.x, f2.y, f2.z, f2.w};
    #pragma unroll
    for (int q = 0; q < 4; ++q) {
      const float* xr = Xk + (size_t)(mc + q)*FD;
      float4 a = *(const float4*)&xr[ca];
      float4 b = *(const float4*)&xr[cb];
      float f = fq[q];
      float av[4] = {a.x*f, a.y*f, a.z*f, a.w*f};
      float bv[4] = {b.x, b.y, b.z, b.w};
      #pragma unroll
      for (int r = 0; r < 4; ++r)
        #pragma unroll
        for (int c = 0; c < 4; ++c) acc[r][c] += av[r]*bv[c];
    }
  }
  float* gp = p.emb + (size_t)z*FD*FD;
  #pragma unroll
  for (int r = 0; r < 4; ++r)
    *(float4*)&gp[(size_t)(ti*64 + ty*4 + r)*FD + cb] =
        make_float4(acc[r][0], acc[r][1], acc[r][2], acc[r][3]);
}

// P3: reduce Gp -> G0 (blocks 0..255); part -> c0 (blocks 256..259)
__device__ void P3(const P& p, int bid, float* sh) {
  int tid = threadIdx.x;
  if (bid < 256) {
    size_t e0 = (size_t)bid*256 + tid;
    float s = 0;
    #pragma unroll 8
    for (int z = 0; z < NZ; ++z) s += p.emb[(size_t)z*FD*FD + e0];
    p.G0[e0] = s;
  } else if (bid < 260) {
    int qb = bid - 256, cl = tid & 63, q = tid >> 6;
    float s = 0;
    for (int j = 0; j < 128; ++j) s += p.part[(size_t)(q*128 + j)*FD + qb*64 + cl];
    sh[q*64 + cl] = s;
    __syncthreads();
    if (tid < 64) p.c0[qb*64 + tid] = sh[tid] + sh[64 + tid] + sh[128 + tid] + sh[192 + tid];
  }
}

// P4: emb' = f0*[X + (X G0 - f0 (X.c0) X)/N]; emits nrm1 + fpart1. No LDS GEMM.
__device__ void P4(const P& p, int bid, float* sh) {
  const int tid = threadIdx.x, wave = tid >> 6, lane = tid & 63;
  const int r0 = bid*16;
  const float invN = 1.f / NROW;
  const float* Xr[4]; float f0r[4];
  #pragma unroll
  for (int r = 0; r < 4; ++r) {
    int row = r0 + wave*4 + r;
    Xr[r] = p.X + (size_t)row*FD; f0r[r] = p.f0[row];
  }
  float4 cc = *(const float4*)&p.c0[lane*4];
  float traw[4];
  #pragma unroll
  for (int r = 0; r < 4; ++r) {
    float4 xv = *(const float4*)&Xr[r][lane*4];
    traw[r] = wred(dot4(xv, cc));
  }
  float acc[4][4] = {};
  for (int m = 0; m < FD; m += 4) {
    float4 g0 = *(const float4*)&p.G0[(size_t)(m+0)*FD + lane*4];
    float4 g1 = *(const float4*)&p.G0[(size_t)(m+1)*FD + lane*4];
    float4 g2 = *(const float4*)&p.G0[(size_t)(m+2)*FD + lane*4];
    float4 g3 = *(const float4*)&p.G0[(size_t)(m+3)*FD + lane*4];
    #pragma unroll
    for (int r = 0; r < 4; ++r) {
      float4 a = *(const float4*)&Xr[r][m];
      acc[r][0] += a.x*g0.x + a.y*g1.x + a.z*g2.x + a.w*g3.x;
      acc[r][1] += a.x*g0.y + a.y*g1.y + a.z*g2.y + a.w*g3.y;
      acc[r][2] += a.x*g0.z + a.y*g1.z + a.z*g2.z + a.w*g3.z;
      acc[r][3] += a.x*g0.w + a.y*g1.w + a.z*g2.w + a.w*g3.w;
    }
  }
  #pragma unroll
  for (int r = 0; r < 4; ++r) {
    int row = r0 + wave*4 + r;
    float4 xa = *(const float4*)&Xr[r][lane*4];
    float fr = f0r[r];
    float w0 = fr*(1.f - fr*traw[r]*invN), w1 = fr*invN;
    float4 o;
    o.x = w0*xa.x + w1*acc[r][0]; o.y = w0*xa.y + w1*acc[r][1];
    o.z = w0*xa.z + w1*acc[r][2]; o.w = w0*xa.w + w1*acc[r][3];
    *(float4*)&p.emb[(size_t)row*FD + lane*4] = o;
    float t = wred(dot4(o, o));
    if (lane == 0) { p.nrm1[row] = t; sh[wave*4 + r] = t; }
  }
  __syncthreads();
  if (tid == 0) { float s = 0; for (int j = 0; j < 16; ++j) s += sh[j]; p.fpart1[bid] = s; }
}

// P5: block0: depth-1 scalars. blocks 1..128: c/w colsum partials (F2_1-free form)
__device__ void P5(const P& p, int bid, float* sh) {
  int tid = threadIdx.x;
  if (bid == 0) {
    float s = p.fpart1[tid] + p.fpart1[tid + 256];
    sh[tid] = s;
    __syncthreads();
    for (int off = 128; off; off >>= 1) {
      if (tid < off) sh[tid] += sh[tid + off];
      __syncthreads();
    }
    if (tid == 0) {
      float F2 = sh[0];
      float a = p.scal[1], b = p.scal[3];
      float sb = (b > 0.f) ? 1.f : ((b < 0.f) ? -1.f : 0.f);
      float B = sb / sqrtf(F2);
      float AB = a * B;
      p.scal[8] = a; p.scal[9] = B; p.scal[10] = AB;
      p.scal[11] = (AB <= 0.f) ? AB*B : 0.f;
    }
  } else if (bid <= 128) {
    int rb = bid - 1, r0 = rb*64;
    if (tid < 64) sh[tid] = p.nrm1[r0 + tid];
    __syncthreads();
    float ca = 0, wa = 0;
    for (int j = 0; j < 64; ++j) {
      float e = p.emb[(size_t)(r0 + j)*FD + tid];
      ca += e; wa += sh[j]*e;
    }
    p.part[(size_t)rb*FD + tid] = ca;
    p.part[(size_t)(128 + rb)*FD + tid] = wa;
  }
}

// P6: s = A1*c - kw*w; u[row] = f1*(emb'.s); v partials
__device__ void P6(const P& p, int bid, float* sh) {
  if (bid >= 128) return;
  int tid = threadIdx.x, wave = tid >> 6, lane = tid & 63;
  float A1 = p.scal[8], B1 = p.scal[9], AB1 = p.scal[10], kw = p.scal[11];
  float ca = 0, wa = 0;
  for (int pb = 0; pb < 128; ++pb) {
    ca += p.part[(size_t)pb*FD + tid];
    wa += p.part[(size_t)(128 + pb)*FD + tid];
  }
  sh[tid] = A1*ca - kw*wa;
  __syncthreads();
  int r0 = bid*64;
  float4 sv = *(const float4*)&sh[lane*4];
  for (int jj = 0; jj < 16; ++jj) {
    int j = wave*16 + jj, row = r0 + j;
    float4 e = *(const float4*)&p.emb[(size_t)row*FD + lane*4];
    float t = wred(dot4(e, sv));
    float f1 = f_of(p.nrm1[row], A1, B1, AB1);
    float uj = f1*t;
    if (lane == 0) { p.u[row] = uj; sh[256 + j] = uj*f1; }
  }
  __syncthreads();
  float va = 0;
  for (int j = 0; j < 64; ++j) va += sh[256 + j] * p.emb[(size_t)(r0 + j)*FD + tid];
  p.part[(size_t)(256 + bid)*FD + tid] = va;
}

// P7: v reduce + out
__device__ void P7(const P& p, int bid, float* sh) {
  int tid = threadIdx.x, wave = tid >> 6, lane = tid & 63;
  float vv = 0;
  for (int pb = 0; pb < 128; ++pb) vv += p.part[(size_t)(256 + pb)*FD + tid];
  sh[tid] = vv;
  __syncthreads();
  float A1 = p.scal[8], B1 = p.scal[9], AB1 = p.scal[10];
  const float invN = 1.f / NROW;
  float4 v4 = *(const float4*)&sh[lane*4];
  int r0 = bid*16;
  #pragma unroll
  for (int r = 0; r < 4; ++r) {
    int row = r0 + wave*4 + r;
    float4 e = *(const float4*)&p.emb[(size_t)row*FD + lane*4];
    float d = wred(dot4(e, v4));
    if (lane == 0 && row < NROW - 1) {
      float f1 = f_of(p.nrm1[row], A1, B1, AB1);
      float uj = p.u[row];
      p.out[row] = (uj + (f1*d - uj*uj)*invN)*invN;
    }
  }
}

__global__ void __launch_bounds__(256, 2) mega(P p) {
  cg::grid_group g = cg::this_grid();
  __shared__ float sh[512];
  int bid = blockIdx.x;
  P0(p, bid, sh); g.sync();
  P1(p, bid, sh); g.sync();
  Pf(p, bid, sh); g.sync();
  P2(p, bid, sh); g.sync();
  P3(p, bid, sh); g.sync();
  P4(p, bid, sh); g.sync();
  P5(p, bid, sh); g.sync();
  P6(p, bid, sh); g.sync();
  P7(p, bid, sh);
}

// fallback wrappers (regular launches, same math) in case cooperative launch fails
__global__ void __launch_bounds__(256) w0(P p){ __shared__ float sh[512]; P0(p, blockIdx.x, sh); }
__global__ void __launch_bounds__(256) w1(P p){ __shared__ float sh[512]; P1(p, blockIdx.x, sh); }
__global__ void __launch_bounds__(256) wf(P p){ __shared__ float sh[512]; Pf(p, blockIdx.x, sh); }
__global__ void __launch_bounds__(256) w2(P p){ __shared__ float sh[512]; P2(p, blockIdx.x, sh); }
__global__ void __launch_bounds__(256) w3(P p){ __shared__ float sh[512]; P3(p, blockIdx.x, sh); }
__global__ void __launch_bounds__(256) w4(P p){ __shared__ float sh[512]; P4(p, blockIdx.x, sh); }
__global__ void __launch_bounds__(256) w5(P p){ __shared__ float sh[512]; P5(p, blockIdx.x, sh); }
__global__ void __launch_bounds__(256) w6(P p){ __shared__ float sh[512]; P6(p, blockIdx.x, sh); }
__global__ void __launch_bounds__(256) w7(P p){ __shared__ float sh[512]; P7(p, blockIdx.x, sh); }

extern "C" void kernel_launch(void* const* d_in, const int* in_sizes, int n_in,
                              void* d_out, int out_size, void* d_ws, size_t ws_size,
                              hipStream_t stream) {
  char* ws = (char*)d_ws;
  P p;
  p.X      = (const float*)d_in[0];
  // d_in[1] = coefs (unused by the reference forward)
  p.linear = (const float*)d_in[2];
  p.dirv   = (const float*)d_in[3];
  p.feat   = (const float*)d_in[4];
  p.out    = (float*)d_out;
  p.scal   = (float*)(ws + 0);
  p.fpart  = (float*)(ws + 1024);
  p.fpart1 = (float*)(ws + 3072);
  p.f0     = (float*)(ws + 8192);
  p.f0sq   = (float*)(ws + 40960);
  p.nrm0   = (float*)(ws + 73728);
  p.nrm1   = (float*)(ws + 106496);
  p.u      = (float*)(ws + 139264);
  p.c0     = (float*)(ws + 172032);
  p.part   = (float*)(ws + 176128);
  p.G0     = (float*)(ws + 700416);
  p.emb    = (float*)(ws + 1048576);

  void* args[] = { &p };
  hipError_t err = hipLaunchCooperativeKernel((const void*)mega, dim3(NB), dim3(256),
                                              args, 0, stream);
  if (err != hipSuccess) {
    // fallback: same phases as regular launches
    w0<<<NB, 256, 0, stream>>>(p);
    w1<<<1, 256, 0, stream>>>(p);
    wf<<<NB, 256, 0, stream>>>(p);
    w2<<<NB, 256, 0, stream>>>(p);
    w3<<<260, 256, 0, stream>>>(p);
    w4<<<NB, 256, 0, stream>>>(p);
    w5<<<129, 256, 0, stream>>>(p);
    w6<<<128, 256, 0, stream>>>(p);
    w7<<<NB, 256, 0, stream>>>(p);
  }
}

// Round 6
// 158.100 us; speedup vs baseline: 3.9154x; 3.9154x over previous
//
#include <hip/hip_runtime.h>
#include <math.h>

constexpr int NROW = 8192;
constexpr int FD   = 256;
constexpr int NZ   = 32;

// ws layout (bytes), total 9437184:
//   0       scal[8]
//   4096    nrm0[8192]    (32 KB)
//   36864   nrm1[8192]    (32 KB)
//   69632   fpart[2048]   (8 KB)
//   77824   fpart1[1024]  (4 KB)
//   81920   cpart[32*256] (32 KB)
//   114688  c0[256]
//   115712  svec[256]
//   116736  vvec[256]
//   117760  u[8192]       (32 KB)
//   150528  G0[65536]     (256 KB)  ends 412672
//   524288  spart[512*256] (512 KB; vpart aliases)
//   1048576 emb[8192*256] (8 MB) — Gp[32][256][256] aliases it pre-apply

__device__ __forceinline__ float f_of(float nj, float A, float B, float AB) {
    float inner = AB * nj;
    return A - (inner <= 0.f ? inner : 0.f) * B;
}

// one wave per row: nrm0[j] = ||row||^2 ; block partial -> fpart
__global__ void k_norm(const float* __restrict__ in, float* __restrict__ nrm,
                       float* __restrict__ fpart) {
    __shared__ float bs[4];
    int wave = threadIdx.x >> 6, lane = threadIdx.x & 63;
    int row = blockIdx.x * 4 + wave;
    const float4 v = *(const float4*)&in[(size_t)row * FD + lane * 4];
    float s = v.x*v.x + v.y*v.y + v.z*v.z + v.w*v.w;
    #pragma unroll
    for (int off = 32; off; off >>= 1) s += __shfl_down(s, off);
    if (lane == 0) { nrm[row] = s; bs[wave] = s; }
    __syncthreads();
    if (threadIdx.x == 0) fpart[blockIdx.x] = bs[0] + bs[1] + bs[2] + bs[3];
}

// 1 block: a,b dots; F2 = sum(fpart); scalars A,B,AB for depth 0
__global__ void k_red(const float* __restrict__ fpart, int n, float* __restrict__ scal,
                      const float* __restrict__ linear, const float* __restrict__ dirv,
                      const float* __restrict__ feat) {
    __shared__ float l[256];
    int tid = threadIdx.x;
    if (tid < 64) {
        for (int i = 0; i < 2; ++i) {
            float pa = 0.f, pb = 0.f;
            for (int k = tid; k < FD; k += 64) {
                float ll = linear[i*FD + k];
                pa += feat[i*FD + k] * ll;
                pb += dirv[i*FD + k] * ll;
            }
            #pragma unroll
            for (int off = 32; off; off >>= 1) {
                pa += __shfl_down(pa, off);
                pb += __shfl_down(pb, off);
            }
            if (tid == 0) { scal[i] = pa; scal[2 + i] = pb; }
        }
    }
    float s = 0.f;
    for (int j = tid; j < n; j += 256) s += fpart[j];
    l[tid] = s;
    __syncthreads();
    for (int off = 128; off; off >>= 1) {
        if (tid < off) l[tid] += l[tid + off];
        __syncthreads();
    }
    if (tid == 0) {
        float F2 = l[0];
        float a = scal[0], b = scal[2];
        float sb = (b > 0.f) ? 1.f : ((b < 0.f) ? -1.f : 0.f);
        float B = sb / sqrtf(F2);
        scal[4] = a; scal[5] = B; scal[6] = a * B; scal[7] = F2;
    }
}

// Gram partials of r0 = f0*X: grid (4,4,32); 64x64 tile, 4x4 acc, K=256 rows per z.
// tj==0 blocks emit cpart[z][ti*64..+64] = colsum of scaled rows in their K-range.
__global__ void __launch_bounds__(256, 2)
k_gram(const float* __restrict__ X, const float* __restrict__ nrm0,
       const float* __restrict__ scal, float* __restrict__ Gp,
       float* __restrict__ cpart) {
    __shared__ float As[32][68];   // stride 68: b128 reads 2-way max (free)
    __shared__ float Bs[32][68];
    __shared__ float frows[256];
    const int ti = blockIdx.x, tj = blockIdx.y, z = blockIdx.z;
    const int m0 = z * (NROW / NZ);            // 256 rows per z
    const int tid = threadIdx.x;
    const int tx = tid & 15, ty = tid >> 4;    // B cols tx*4, A cols ty*4
    const int p = tid & 63, q = tid >> 6;
    const float A = scal[4], B = scal[5], AB = scal[6];
    // per-block f values for all 256 K-rows, once
    frows[tid] = f_of(nrm0[m0 + tid], A, B, AB);
    float acc[4][4] = {};
    float cs = 0.f;
    for (int mc = 0; mc < 256; mc += 32) {
        __syncthreads();
        #pragma unroll
        for (int r = 0; r < 2; ++r) {
            int idx = tid + r * 256;
            int mm = idx >> 4, c4 = (idx & 15) << 2;
            float f = frows[mc + mm];
            const float* rp = X + (size_t)(m0 + mc + mm) * FD;
            float4 a = *(const float4*)&rp[ti*64 + c4];
            float4 b = *(const float4*)&rp[tj*64 + c4];
            a.x *= f; a.y *= f; a.z *= f; a.w *= f;
            b.x *= f; b.y *= f; b.z *= f; b.w *= f;
            *(float4*)&As[mm][c4] = a;
            *(float4*)&Bs[mm][c4] = b;
        }
        __syncthreads();
        #pragma unroll 8
        for (int mm = 0; mm < 32; ++mm) {
            float4 a4 = *(const float4*)&As[mm][ty*4];
            float4 b4 = *(const float4*)&Bs[mm][tx*4];
            float av[4] = {a4.x, a4.y, a4.z, a4.w};
            float bv[4] = {b4.x, b4.y, b4.z, b4.w};
            #pragma unroll
            for (int r = 0; r < 4; ++r)
                #pragma unroll
                for (int cc = 0; cc < 4; ++cc)
                    acc[r][cc] += av[r] * bv[cc];
        }
        if (tj == 0) {
            #pragma unroll
            for (int s = 0; s < 8; ++s) cs += As[q*8 + s][p];
        }
    }
    float* gp = Gp + (size_t)z * (FD * FD);
    #pragma unroll
    for (int r = 0; r < 4; ++r) {
        float4 o = make_float4(acc[r][0], acc[r][1], acc[r][2], acc[r][3]);
        *(float4*)&gp[(ti*64 + ty*4 + r)*FD + tj*64 + tx*4] = o;
    }
    if (tj == 0) {
        __syncthreads();
        ((float*)As)[tid] = cs;            // tid = q*64 + p
        __syncthreads();
        if (tid < 64)
            cpart[z*FD + ti*64 + tid] = ((float*)As)[tid] + ((float*)As)[64 + tid] +
                                        ((float*)As)[128 + tid] + ((float*)As)[192 + tid];
    }
}

// blocks 0..255: G0 = sum_z Gp ; block 256: c0 = sum_z cpart
__global__ void k_gred(const float* __restrict__ Gp, const float* __restrict__ cpart,
                       float* __restrict__ G0, float* __restrict__ c0) {
    int tid = threadIdx.x;
    if (blockIdx.x < 256) {
        int e0 = blockIdx.x * 256 + tid;
        float s = 0.f;
        #pragma unroll 8
        for (int z = 0; z < NZ; ++z) s += Gp[(size_t)z * (FD * FD) + e0];
        G0[e0] = s;
    } else {
        float s = 0.f;
        #pragma unroll 8
        for (int z = 0; z < NZ; ++z) s += cpart[z*FD + tid];
        c0[tid] = s;
    }
}

// emb'[j] = r_j + (r_j@G0 - (r_j.c0) r_j)/N , r_j = f0_j X_j.
// 256 thr, 8 rows/block, 1024 blocks (4 blocks/CU). Emits nrm1 + fpart1[1024].
__global__ void __launch_bounds__(256, 8)
k_apply(const float* __restrict__ X, const float* __restrict__ nrm0,
        const float* __restrict__ scal, const float* __restrict__ G0,
        const float* __restrict__ c0, float* __restrict__ emb,
        float* __restrict__ nrm1, float* __restrict__ fpart1) {
    __shared__ float rows[8][FD + 4];
    __shared__ float csh[FD];
    __shared__ float ff[8];
    __shared__ float u0[8];
    __shared__ float np[4][8];
    const int tid = threadIdx.x;
    const int r0 = blockIdx.x * 8;
    const float A = scal[4], B = scal[5], AB = scal[6];

    csh[tid] = c0[tid];
    if (tid < 8) ff[tid] = f_of(nrm0[r0 + tid], A, B, AB);
    __syncthreads();

    #pragma unroll
    for (int r = 0; r < 2; ++r) {
        int idx = tid + r * 256;
        int j = idx >> 6, c4 = (idx & 63) << 2;
        float4 v = *(const float4*)&X[(size_t)(r0 + j) * FD + c4];
        float f = ff[j];
        v.x *= f; v.y *= f; v.z *= f; v.w *= f;
        *(float4*)&rows[j][c4] = v;
    }
    __syncthreads();

    const int wave = tid >> 6, lane = tid & 63;
    #pragma unroll
    for (int jj = 0; jj < 2; ++jj) {
        int j = wave * 2 + jj;
        float4 rv = *(const float4*)&rows[j][lane*4];
        float4 cc = *(const float4*)&csh[lane*4];
        float s = rv.x*cc.x + rv.y*cc.y + rv.z*cc.z + rv.w*cc.w;
        #pragma unroll
        for (int off = 32; off; off >>= 1) s += __shfl_down(s, off);
        if (lane == 0) u0[j] = s;
    }
    __syncthreads();

    const int rq = lane >> 4, cx = lane & 15;
    const int c0w = wave * 64 + cx * 4;    // 4 output cols
    const int jb = rq * 2;                 // 2 rows
    float acc[2][4] = {};
    for (int m = 0; m < FD; m += 4) {
        float4 g0 = *(const float4*)&G0[(m+0)*FD + c0w];
        float4 g1 = *(const float4*)&G0[(m+1)*FD + c0w];
        float4 g2 = *(const float4*)&G0[(m+2)*FD + c0w];
        float4 g3 = *(const float4*)&G0[(m+3)*FD + c0w];
        #pragma unroll
        for (int jj = 0; jj < 2; ++jj) {
            float4 rv = *(const float4*)&rows[jb + jj][m];
            acc[jj][0] += rv.x*g0.x + rv.y*g1.x + rv.z*g2.x + rv.w*g3.x;
            acc[jj][1] += rv.x*g0.y + rv.y*g1.y + rv.z*g2.y + rv.w*g3.y;
            acc[jj][2] += rv.x*g0.z + rv.y*g1.z + rv.z*g2.z + rv.w*g3.z;
            acc[jj][3] += rv.x*g0.w + rv.y*g1.w + rv.z*g2.w + rv.w*g3.w;
        }
    }

    const float invN = 1.0f / NROW;
    float ssl[2];
    #pragma unroll
    for (int jj = 0; jj < 2; ++jj) {
        int j = jb + jj;
        float4 v = *(const float4*)&rows[j][c0w];
        float uj = u0[j];
        float4 o;
        o.x = v.x + (acc[jj][0] - uj*v.x) * invN;
        o.y = v.y + (acc[jj][1] - uj*v.y) * invN;
        o.z = v.z + (acc[jj][2] - uj*v.z) * invN;
        o.w = v.w + (acc[jj][3] - uj*v.w) * invN;
        *(float4*)&emb[(size_t)(r0 + j) * FD + c0w] = o;
        ssl[jj] = o.x*o.x + o.y*o.y + o.z*o.z + o.w*o.w;
    }
    #pragma unroll
    for (int jj = 0; jj < 2; ++jj) {
        float s = ssl[jj];
        #pragma unroll
        for (int off = 8; off; off >>= 1) s += __shfl_down(s, off);
        if (cx == 0) np[wave][jb + jj] = s;
    }
    __syncthreads();
    if (tid < 8) {
        float nn = np[0][tid] + np[1][tid] + np[2][tid] + np[3][tid];
        nrm1[r0 + tid] = nn;
        ff[tid] = nn;
    }
    __syncthreads();
    if (tid == 0) {
        float fp = 0.f;
        #pragma unroll
        for (int j = 0; j < 8; ++j) fp += ff[j];
        fpart1[blockIdx.x] = fp;
    }
}

// depth-1 scalars recomputed per block from fpart1[1024]
__device__ __forceinline__ void red1_scal(const float* fpart1, const float* scal,
                                          float* l, float& A, float& B, float& AB) {
    int tid = threadIdx.x;
    float s = fpart1[tid] + fpart1[tid + 256] + fpart1[tid + 512] + fpart1[tid + 768];
    l[tid] = s;
    __syncthreads();
    for (int off = 128; off; off >>= 1) {
        if (tid < off) l[tid] += l[tid + off];
        __syncthreads();
    }
    float F2 = l[0];
    float a = scal[1], b = scal[3];
    float sb = (b > 0.f) ? 1.f : ((b < 0.f) ? -1.f : 0.f);
    B = sb / sqrtf(F2);
    A = a; AB = a * B;
    __syncthreads();
}

// spart[bid][col] = sum_{16 rows} f1_j emb'[j][col]
__global__ void k_colsum(const float* __restrict__ emb, const float* __restrict__ nrm1,
                         const float* __restrict__ scal, const float* __restrict__ fpart1,
                         float* __restrict__ spart) {
    __shared__ float l[256];
    __shared__ float ffs[16];
    float A, B, AB;
    red1_scal(fpart1, scal, l, A, B, AB);
    int tid = threadIdx.x;
    int r0 = blockIdx.x * 16;
    if (tid < 16) ffs[tid] = f_of(nrm1[r0 + tid], A, B, AB);
    __syncthreads();
    float s = 0.f;
    #pragma unroll
    for (int j = 0; j < 16; ++j)
        s += ffs[j] * emb[(size_t)(r0 + j) * FD + tid];
    spart[(size_t)blockIdx.x * FD + tid] = s;
}

// reduce part[512][256] -> vec[256]; grid 64 x 256 thr (4 cols/block)
__global__ void k_sred(const float* __restrict__ part, float* __restrict__ vec) {
    int tid = threadIdx.x;
    int col = blockIdx.x * 4 + (tid >> 6);
    int lane = tid & 63;
    float s = 0.f;
    #pragma unroll
    for (int b = 0; b < 8; ++b) s += part[(size_t)(b * 64 + lane) * FD + col];
    #pragma unroll
    for (int off = 32; off; off >>= 1) s += __shfl_down(s, off);
    if (lane == 0) vec[col] = s;
}

// u[row] = f1 (emb'_row . s) ; vpart[bid][col] = sum_j (u_j f1_j) emb'[j][col]
__global__ void k_uv(const float* __restrict__ emb, const float* __restrict__ nrm1,
                     const float* __restrict__ scal, const float* __restrict__ fpart1,
                     const float* __restrict__ svec, float* __restrict__ u,
                     float* __restrict__ vpart) {
    __shared__ float l[256];
    __shared__ float ssh[FD];
    __shared__ float uf[16];
    float A, B, AB;
    red1_scal(fpart1, scal, l, A, B, AB);
    int tid = threadIdx.x;
    int r0 = blockIdx.x * 16;
    ssh[tid] = svec[tid];
    __syncthreads();
    const int wave = tid >> 6, lane = tid & 63;
    float4 sv = *(const float4*)&ssh[lane*4];
    #pragma unroll
    for (int jj = 0; jj < 4; ++jj) {
        int row = r0 + wave * 4 + jj;
        float4 ev = *(const float4*)&emb[(size_t)row * FD + lane*4];
        float s = ev.x*sv.x + ev.y*sv.y + ev.z*sv.z + ev.w*sv.w;
        #pragma unroll
        for (int off = 32; off; off >>= 1) s += __shfl_down(s, off);
        if (lane == 0) {
            float f = f_of(nrm1[row], A, B, AB);
            float uj = f * s;
            u[row] = uj;
            uf[wave*4 + jj] = uj * f;
        }
    }
    __syncthreads();
    float vp = 0.f;
    #pragma unroll
    for (int j = 0; j < 16; ++j)
        vp += uf[j] * emb[(size_t)(r0 + j) * FD + tid];
    vpart[(size_t)blockIdx.x * FD + tid] = vp;
}

// out[row] = (u + (f1*(emb'_row . v) - u^2)/N)/N
__global__ void k_out(const float* __restrict__ emb, const float* __restrict__ nrm1,
                      const float* __restrict__ scal, const float* __restrict__ fpart1,
                      const float* __restrict__ vvec, const float* __restrict__ u,
                      float* __restrict__ out) {
    __shared__ float l[256];
    __shared__ float vsh[FD];
    float A, B, AB;
    red1_scal(fpart1, scal, l, A, B, AB);
    int tid = threadIdx.x;
    int r0 = blockIdx.x * 16;
    vsh[tid] = vvec[tid];
    __syncthreads();
    const int wave = tid >> 6, lane = tid & 63;
    const float invN = 1.0f / NROW;
    float4 vv = *(const float4*)&vsh[lane*4];
    #pragma unroll
    for (int jj = 0; jj < 4; ++jj) {
        int row = r0 + wave * 4 + jj;
        float4 ev = *(const float4*)&emb[(size_t)row * FD + lane*4];
        float s = ev.x*vv.x + ev.y*vv.y + ev.z*vv.z + ev.w*vv.w;
        #pragma unroll
        for (int off = 32; off; off >>= 1) s += __shfl_down(s, off);
        if (lane == 0 && row < NROW - 1) {
            float f = f_of(nrm1[row], A, B, AB);
            float uj = u[row];
            out[row] = (uj + (f * s - uj * uj) * invN) * invN;
        }
    }
}

extern "C" void kernel_launch(void* const* d_in, const int* in_sizes, int n_in,
                              void* d_out, int out_size, void* d_ws, size_t ws_size,
                              hipStream_t stream) {
    const float* X      = (const float*)d_in[0];
    // d_in[1] = coefs (unused by the reference forward)
    const float* linear = (const float*)d_in[2];
    const float* dirv   = (const float*)d_in[3];
    const float* feat   = (const float*)d_in[4];
    float* out = (float*)d_out;

    char* ws = (char*)d_ws;
    float* scal   = (float*)(ws + 0);
    float* nrm0   = (float*)(ws + 4096);
    float* nrm1   = (float*)(ws + 36864);
    float* fpart  = (float*)(ws + 69632);
    float* fpart1 = (float*)(ws + 77824);
    float* cpart  = (float*)(ws + 81920);
    float* c0     = (float*)(ws + 114688);
    float* svec   = (float*)(ws + 115712);
    float* vvec   = (float*)(ws + 116736);
    float* u      = (float*)(ws + 117760);
    float* G0     = (float*)(ws + 150528);
    float* spart  = (float*)(ws + 524288);   // vpart aliases spart
    float* emb    = (float*)(ws + 1048576);
    float* Gp     = emb;                     // Gp lives in emb region pre-apply

    k_norm<<<NROW/4, 256, 0, stream>>>(X, nrm0, fpart);
    k_red<<<1, 256, 0, stream>>>(fpart, 2048, scal, linear, dirv, feat);
    k_gram<<<dim3(4,4,NZ), 256, 0, stream>>>(X, nrm0, scal, Gp, cpart);
    k_gred<<<257, 256, 0, stream>>>(Gp, cpart, G0, c0);
    k_apply<<<NROW/8, 256, 0, stream>>>(X, nrm0, scal, G0, c0, emb, nrm1, fpart1);
    k_colsum<<<NROW/16, 256, 0, stream>>>(emb, nrm1, scal, fpart1, spart);
    k_sred<<<64, 256, 0, stream>>>(spart, svec);
    k_uv<<<NROW/16, 256, 0, stream>>>(emb, nrm1, scal, fpart1, svec, u, spart);
    k_sred<<<64, 256, 0, stream>>>(spart, vvec);
    k_out<<<NROW/16, 256, 0, stream>>>(emb, nrm1, scal, fpart1, vvec, u, out);
}